// Round 14
// baseline (87.421 us; speedup 1.0000x reference)
//
#include <hip/hip_runtime.h>
#include <math.h>

#define B_    32
#define H_    28
#define W_    28
#define C_    768
#define D_    64
#define EMB_  64
#define HW_   (H_ * W_)
#define NPOS  (B_ * HW_)          // 25088
#define CWROWS (D_ * D_ * 9)      // 36864

typedef __attribute__((ext_vector_type(8))) short bf16x8;
typedef __attribute__((ext_vector_type(4))) float f32x4;

__device__ __forceinline__ float qgelu(float v) {
    return v / (1.f + __expf(-1.702f * v));
}
__device__ __forceinline__ float relu(float v) { return fmaxf(v, 0.f); }

// fp32 -> bf16 RTNE
__device__ __forceinline__ ushort f2bf(float f) {
    union { float f; unsigned u; } v; v.f = f;
    return (ushort)((v.u + 0x7fffu + ((v.u >> 16) & 1u)) >> 16);
}

// XOR-swizzled LDS tile address: rows are 128 B (64 bf16); byte offset within
// row is kbyte ^ ((row&7)<<4) -> b128 reads across 16 rows are <=2-way (free).
__device__ __forceinline__ void* swz(void* base, int row, int kbyte) {
    return (void*)((char*)base + row * 128 + (kbyte ^ ((row & 7) << 4)));
}

// async global->LDS, 16 B per lane; LDS dest is wave-uniform base + lane*16
typedef const __attribute__((address_space(1))) void g_void;
typedef __attribute__((address_space(3))) void l_void;
__device__ __forceinline__ void gload16(const void* g, void* l) {
    __builtin_amdgcn_global_load_lds((g_void*)g, (l_void*)l, 16, 0, 0);
}

// ---------------- Stage 0: weight convert fp32 -> bf16, pre-tiled+swizzled ----------------
// wcat2: 12 tiles of [n(128)][kk(64)]; element (kb,n,kk) at kb*8192 + n*64 + (kk ^ ((n&7)<<3))
// wup2:  [n(768)][kk(64)] with kk ^ ((n&7)<<3)  (up_w rows)
__global__ void k_cvt(const float* __restrict__ w1, const float* __restrict__ dw,
                      const float* __restrict__ uw,
                      ushort* __restrict__ wcat2, ushort* __restrict__ wup2)
{
    const int f = (blockIdx.x * 256 + threadIdx.x) * 4;   // 147456 total
    float4 v;
    size_t dst;
    ushort* base;
    if (f < 98304) {
        int n, k;
        if (f < 49152) { n = f / 768;            k = f % 768; v = *(const float4*)(w1 + (size_t)n * 768 + k); }
        else           { int g = f - 49152; n = 64 + g / 768; k = g % 768; v = *(const float4*)(dw + (size_t)(n - 64) * 768 + k); }
        const int kb = k >> 6, kk = k & 63;
        dst  = (size_t)kb * 8192 + n * 64 + (kk ^ ((n & 7) << 3));
        base = wcat2;
    } else {
        const int g = f - 98304;                 // over [768][64]
        const int n = g >> 6, kk = g & 63;
        v = *(const float4*)(uw + g);
        dst  = (size_t)n * 64 + (kk ^ ((n & 7) << 3));
        base = wup2;
    }
    union { ushort u[4]; uint2 p; } o;
    o.u[0] = f2bf(v.x); o.u[1] = f2bf(v.y); o.u[2] = f2bf(v.z); o.u[3] = f2bf(v.w);
    *(uint2*)(base + dst) = o.p;
}

// ---------------- Stage 1+4: MFMA GEMM  M=25088 N=128 K=768 ----------------
// block 32m x 128n, 4 waves = 1m x 4n grid, wave-tile 32x32. 784 blocks.
__global__ __launch_bounds__(256)
void k_gemm_md(const float* __restrict__ x, const ushort* __restrict__ wcat2,
               const float* __restrict__ b1, const float* __restrict__ db,
               float* __restrict__ hbuf, ushort* __restrict__ xact)
{
    __shared__ ushort As[32 * 64];    //  4 KB, [m][k] swizzled
    __shared__ ushort Bs[128 * 64];   // 16 KB, linear image of wcat2 tile (pre-swizzled)
    const int t = threadIdx.x;
    const int wid = t >> 6, lane = t & 63;
    const int lo = lane & 15, hi = lane >> 4;
    const int bm = blockIdx.x;                 // 784

    f32x4 acc[2][2] = {};

    const int arow = t >> 3, akq = t & 7;      // 256 thr cover 32 rows x 8 ksegs
    const float* asrc = x + (size_t)(bm * 32 + arow) * C_ + akq * 8;

    float4 p0 = *(const float4*)(asrc);
    float4 p1 = *(const float4*)(asrc + 4);

    for (int k0 = 0; k0 < C_; k0 += 64) {
        __syncthreads();
        {   // store A tile from prefetch regs (fp32 -> bf16)
            union { ushort u[8]; float4 v; } tmp;
            tmp.u[0] = f2bf(p0.x); tmp.u[1] = f2bf(p0.y);
            tmp.u[2] = f2bf(p0.z); tmp.u[3] = f2bf(p0.w);
            tmp.u[4] = f2bf(p1.x); tmp.u[5] = f2bf(p1.y);
            tmp.u[6] = f2bf(p1.z); tmp.u[7] = f2bf(p1.w);
            *(float4*)swz(As, arow, akq * 16) = tmp.v;
        }
        {   // B tile: async DMA, 16 chunks of 1 KB (4 per wave) == 16 KB == Bs
            const ushort* bsrc = wcat2 + (size_t)(k0 >> 6) * 8192;
            #pragma unroll
            for (int c = 0; c < 4; ++c) {
                const int cbase = (wid * 4 + c) * 512;
                gload16(bsrc + cbase + lane * 8, (ushort*)Bs + cbase);
            }
        }
        if (k0 + 64 < C_) {
            p0 = *(const float4*)(asrc + k0 + 64);
            p1 = *(const float4*)(asrc + k0 + 68);
        }
        __syncthreads();   // compiler-inserted vmcnt(0) drains the gload_lds

        #pragma unroll
        for (int ks = 0; ks < 2; ++ks) {
            bf16x8 a[2], b[2];
            #pragma unroll
            for (int i = 0; i < 2; ++i)
                a[i] = *(const bf16x8*)swz(As, i * 16 + lo, ks * 64 + hi * 16);
            #pragma unroll
            for (int j = 0; j < 2; ++j)
                b[j] = *(const bf16x8*)swz(Bs, wid * 32 + j * 16 + lo, ks * 64 + hi * 16);
            #pragma unroll
            for (int i = 0; i < 2; ++i)
                #pragma unroll
                for (int j = 0; j < 2; ++j)
                    acc[i][j] = __builtin_amdgcn_mfma_f32_16x16x32_bf16(a[i], b[j], acc[i][j], 0, 0, 0);
        }
    }

    #pragma unroll
    for (int j = 0; j < 2; ++j) {
        const int n = wid * 32 + j * 16 + lo;    // 0..127, uniform half per wave
        if (n < 64) {
            const float bias = b1[n];
            #pragma unroll
            for (int i = 0; i < 2; ++i)
                #pragma unroll
                for (int r = 0; r < 4; ++r) {
                    int pos = bm * 32 + i * 16 + hi * 4 + r;
                    hbuf[(size_t)pos * 64 + n] = relu(acc[i][j][r] + bias);
                }
        } else {
            const float bias = db[n - 64];
            #pragma unroll
            for (int i = 0; i < 2; ++i)
                #pragma unroll
                for (int r = 0; r < 4; ++r) {
                    int pos = bm * 32 + i * 16 + hi * 4 + r;
                    xact[(size_t)pos * 64 + (n - 64)] = f2bf(qgelu(acc[i][j][r] + bias));
                }
        }
    }
}

// ---------------- Stage 2a: partial spatial sum (b, quarter) ----------------
__global__ void k_reduce1(const float* __restrict__ hbuf, float* __restrict__ partial)
{
    __shared__ float part[16][EMB_];
    const int b = blockIdx.x, q = blockIdx.y;
    const int tid = threadIdx.x;
    const int e4 = tid & 15, pc = tid >> 4;

    const float* base = hbuf + ((size_t)b * HW_ + q * 196) * 64 + e4 * 4;
    float4 acc = make_float4(0.f, 0.f, 0.f, 0.f);
    for (int i = pc; i < 196; i += 16) {
        float4 v = *(const float4*)(base + (size_t)i * 64);
        acc.x += v.x; acc.y += v.y; acc.z += v.z; acc.w += v.w;
    }
    part[pc][e4 * 4 + 0] = acc.x;
    part[pc][e4 * 4 + 1] = acc.y;
    part[pc][e4 * 4 + 2] = acc.z;
    part[pc][e4 * 4 + 3] = acc.w;
    __syncthreads();
    if (tid < EMB_) {
        float s = 0.f;
        #pragma unroll
        for (int c = 0; c < 16; ++c) s += part[c][tid];
        partial[(size_t)(b * 4 + q) * EMB_ + tid] = s;
    }
}

// ---------------- Stage 2b+3 fused: mean + meta2 + hypernet ----------------
// grid (144, 2): block = 256 hyper_w rows x 16 batches -> hyper_w read 2x total
// (was 4x). Each thread keeps one row in VGPRs and loops 16 batches.
__global__ void k_hyper(const float* __restrict__ partial, const float* __restrict__ layer_emb,
                        const float* __restrict__ w2, const float* __restrict__ b2,
                        const float* __restrict__ hyper_w, const float* __restrict__ hyper_b,
                        ushort* __restrict__ cwb)
{
    __shared__ float w2L[64][65];      // padded: dot reads conflict-free
    __shared__ float hmL[16][EMB_];
    __shared__ float fusedL[16][EMB_];
    const int tid = threadIdx.x;
    const int b0 = blockIdx.y * 16;

    for (int i = tid; i < 1024; i += 256) {
        int r = i >> 4, c = (i & 15) * 4;
        float4 v = *(const float4*)(w2 + (size_t)r * 64 + c);
        w2L[r][c] = v.x; w2L[r][c + 1] = v.y; w2L[r][c + 2] = v.z; w2L[r][c + 3] = v.w;
    }
    for (int i = tid; i < 1024; i += 256) {
        int bl = i >> 6, e = i & 63;
        const float* pp = partial + (size_t)((b0 + bl) * 4) * EMB_ + e;
        float s = pp[0] + pp[64] + pp[128] + pp[192];
        hmL[bl][e] = s * (1.f / HW_);
    }
    __syncthreads();
    for (int i = tid; i < 1024; i += 256) {
        int bl = i >> 6, e = i & 63;
        float a0 = 0.f, a1 = 0.f, a2 = 0.f, a3 = 0.f;
        #pragma unroll
        for (int k = 0; k < EMB_; k += 4) {
            a0 = fmaf(hmL[bl][k + 0], w2L[e][k + 0], a0);
            a1 = fmaf(hmL[bl][k + 1], w2L[e][k + 1], a1);
            a2 = fmaf(hmL[bl][k + 2], w2L[e][k + 2], a2);
            a3 = fmaf(hmL[bl][k + 3], w2L[e][k + 3], a3);
        }
        fusedL[bl][e] = (a0 + a1) + (a2 + a3) + b2[e] + layer_emb[e];
    }
    __syncthreads();

    const int f    = blockIdx.x * 256 + tid;
    const int din  = f & 63;
    const int dout = (f >> 6) & 63;
    const int tap  = f >> 12;
    const int r    = (dout * 64 + din) * 9 + tap;

    float wrow[EMB_];
    const float4* hw4 = (const float4*)(hyper_w + (size_t)r * EMB_);
    #pragma unroll
    for (int i = 0; i < EMB_ / 4; ++i) {
        float4 v = hw4[i];
        wrow[i*4+0] = v.x; wrow[i*4+1] = v.y; wrow[i*4+2] = v.z; wrow[i*4+3] = v.w;
    }
    const float hb = hyper_b[r];

    for (int bl = 0; bl < 16; ++bl) {
        float a0 = 0.f, a1 = 0.f, a2 = 0.f, a3 = 0.f;
        #pragma unroll
        for (int i = 0; i < EMB_; i += 4) {
            a0 = fmaf(fusedL[bl][i+0], wrow[i+0], a0);
            a1 = fmaf(fusedL[bl][i+1], wrow[i+1], a1);
            a2 = fmaf(fusedL[bl][i+2], wrow[i+2], a2);
            a3 = fmaf(fusedL[bl][i+3], wrow[i+3], a3);
        }
        cwb[(size_t)(b0 + bl) * CWROWS + f] = f2bf((a0 + a1) + (a2 + a3) + hb);
    }
}

// ---------------- Stage 5+6 fused: 3x3 conv + QuickGELU + adapter-up ----------------
// block = (b,h), 8 waves. Conv: 2 M-tiles (w) x 4 N-tiles (dout), K=9x64.
// Then yt tile (32x64 bf16, LDS) becomes A for up-GEMM N=768 K=64.
__global__ __launch_bounds__(512)
void k_convup(const ushort* __restrict__ xact, const ushort* __restrict__ cwb,
              const ushort* __restrict__ wup2, const float* __restrict__ ub,
              float* __restrict__ out)
{
    __shared__ ushort wsl[192 * 64];   // conv weights, 24 KB; reused as Bs (16 KB)
    __shared__ ushort xs[34 * 64];     // x row + halo, 4.25 KB; reused as yt (4 KB)
    const int t = threadIdx.x;
    const int lane = t & 63;
    const int lo = lane & 15, hi = lane >> 4;
    const int b = blockIdx.x / H_;
    const int h = blockIdx.x % H_;
    const int mw = (t >> 6) >> 2;      // 0..1
    const int nw = (t >> 6) & 3;       // 0..3
    const int w0 = mw * 16;

    f32x4 acc = {};

    for (int kh = 0; kh < 3; ++kh) {
        const int hh = h + kh - 1;
        __syncthreads();
        const ushort* wsrc = cwb + (size_t)b * CWROWS + (size_t)kh * 3 * 4096;
        #pragma unroll
        for (int s = 0; s < 3; ++s) {
            int j = s * 512 + t;
            *(float4*)swz(wsl, j >> 3, (j & 7) * 16) = *(const float4*)(wsrc + j * 8);
        }
        if (t < 272) {
            int c = t >> 3, kseg = t & 7;
            int w = c - 1;
            float4 v = make_float4(0.f, 0.f, 0.f, 0.f);
            if (hh >= 0 && hh < H_ && w >= 0 && w < W_)
                v = *(const float4*)(xact + ((size_t)((b * H_ + hh) * W_) + w) * 64 + kseg * 8);
            *(float4*)swz(xs, c, kseg * 16) = v;
        }
        __syncthreads();
        #pragma unroll
        for (int kw = 0; kw < 3; ++kw) {
            #pragma unroll
            for (int ks = 0; ks < 2; ++ks) {
                bf16x8 a  = *(const bf16x8*)swz(xs, w0 + lo + kw, ks * 64 + hi * 16);
                bf16x8 bf = *(const bf16x8*)swz(wsl, kw * 64 + nw * 16 + lo, ks * 64 + hi * 16);
                acc = __builtin_amdgcn_mfma_f32_16x16x32_bf16(a, bf, acc, 0, 0, 0);
            }
        }
    }

    // ---- transition: qgelu tile -> yt (A-operand for up GEMM) ----
    __syncthreads();                    // all conv LDS reads complete
    ushort* yt = xs;                    // 32 rows x 64 k, swizzled (rows 28-31 = 0)
    const int dout = nw * 16 + lo;
    #pragma unroll
    for (int r = 0; r < 4; ++r) {
        int w = w0 + hi * 4 + r;
        *(ushort*)swz(yt, w, dout * 2) = f2bf(qgelu(acc[r]));
    }
    __syncthreads();                    // yt visible

    // hoist A fragments (constant across n-chunks)
    bf16x8 af[2];
    #pragma unroll
    for (int ks = 0; ks < 2; ++ks)
        af[ks] = *(const bf16x8*)swz(yt, mw * 16 + lo, ks * 64 + hi * 16);

    ushort* Bs = wsl;                   // 128 x 64 bf16 per chunk
    const size_t pos0 = (size_t)(b * H_ + h) * W_;

    for (int nc = 0; nc < 6; ++nc) {
        {   // stage Bs: 16 chunks of 1 KB (2 per wave), pre-swizzled source
            const ushort* bsrc = wup2 + (size_t)nc * 8192;
            const int wid = t >> 6;
            #pragma unroll
            for (int c = 0; c < 2; ++c) {
                const int cbase = (wid * 2 + c) * 512;
                gload16(bsrc + cbase + lane * 8, Bs + cbase);
            }
        }
        __syncthreads();                // vmcnt(0) drain

        f32x4 uacc[2] = {};
        #pragma unroll
        for (int ks = 0; ks < 2; ++ks) {
            bf16x8 bb[2];
            #pragma unroll
            for (int j = 0; j < 2; ++j)
                bb[j] = *(const bf16x8*)swz(Bs, nw * 32 + j * 16 + lo, ks * 64 + hi * 16);
            #pragma unroll
            for (int j = 0; j < 2; ++j)
                uacc[j] = __builtin_amdgcn_mfma_f32_16x16x32_bf16(af[ks], bb[j], uacc[j], 0, 0, 0);
        }

        #pragma unroll
        for (int j = 0; j < 2; ++j) {
            const int n = nc * 128 + nw * 32 + j * 16 + lo;
            const float bias = ub[n];
            #pragma unroll
            for (int r = 0; r < 4; ++r) {
                int m = mw * 16 + hi * 4 + r;
                if (m < W_)
                    out[(pos0 + m) * C_ + n] = uacc[j][r] + bias;
            }
        }
        __syncthreads();                // Bs reads done before next overwrite
    }
}

extern "C" void kernel_launch(void* const* d_in, const int* in_sizes, int n_in,
                              void* d_out, int out_size, void* d_ws, size_t ws_size,
                              hipStream_t stream) {
    const float* x         = (const float*)d_in[0];
    const float* meta_w1   = (const float*)d_in[1];
    const float* meta_b1   = (const float*)d_in[2];
    const float* meta_w2   = (const float*)d_in[3];
    const float* meta_b2   = (const float*)d_in[4];
    const float* layer_emb = (const float*)d_in[5];
    const float* hyper_w   = (const float*)d_in[6];
    const float* hyper_b   = (const float*)d_in[7];
    const float* down_w    = (const float*)d_in[8];
    const float* down_b    = (const float*)d_in[9];
    const float* up_w      = (const float*)d_in[10];
    const float* up_b      = (const float*)d_in[11];
    float* out = (float*)d_out;

    char* p = (char*)d_ws;
    float*  hbuf    = (float*)p;           p += (size_t)NPOS * 64 * 4;
    ushort* xact    = (ushort*)p;          p += (size_t)NPOS * 64 * 2;
    float*  partial = (float*)p;           p += (size_t)B_ * 4 * EMB_ * 4;
    ushort* cwb     = (ushort*)p;          p += (size_t)B_ * CWROWS * 2;
    ushort* wcat2   = (ushort*)p;          p += (size_t)128 * C_ * 2;
    ushort* wup2    = (ushort*)p;

    k_cvt<<<144, 256, 0, stream>>>(meta_w1, down_w, up_w, wcat2, wup2);
    k_gemm_md<<<NPOS / 32, 256, 0, stream>>>(x, wcat2, meta_b1, down_b, hbuf, xact);
    k_reduce1<<<dim3(B_, 4), 256, 0, stream>>>(hbuf, partial);
    dim3 hgrid(CWROWS / 256, 2);
    k_hyper<<<hgrid, 256, 0, stream>>>(partial, layer_emb, meta_w2, meta_b2,
                                       hyper_w, hyper_b, cwb);
    k_convup<<<B_ * H_, 512, 0, stream>>>(xact, cwb, wup2, up_b, out);
}

// Round 15
// 69.942 us; speedup vs baseline: 1.2499x; 1.2499x over previous
//
#include <hip/hip_runtime.h>
#include <math.h>

#define B_    32
#define H_    28
#define W_    28
#define C_    768
#define D_    64
#define EMB_  64
#define HW_   (H_ * W_)
#define NPOS  (B_ * HW_)          // 25088
#define CWROWS (D_ * D_ * 9)      // 36864

typedef __attribute__((ext_vector_type(8))) short bf16x8;
typedef __attribute__((ext_vector_type(4))) float f32x4;

__device__ __forceinline__ float qgelu(float v) {
    return v / (1.f + __expf(-1.702f * v));
}
__device__ __forceinline__ float relu(float v) { return fmaxf(v, 0.f); }

// fp32 -> bf16 RTNE
__device__ __forceinline__ ushort f2bf(float f) {
    union { float f; unsigned u; } v; v.f = f;
    return (ushort)((v.u + 0x7fffu + ((v.u >> 16) & 1u)) >> 16);
}

// XOR-swizzled LDS tile address: rows are 128 B (64 bf16); byte offset within
// row is kbyte ^ ((row&7)<<4) -> b128 reads across 16 rows are <=2-way (free).
__device__ __forceinline__ void* swz(void* base, int row, int kbyte) {
    return (void*)((char*)base + row * 128 + (kbyte ^ ((row & 7) << 4)));
}

// async global->LDS, 16 B per lane; LDS dest is wave-uniform base + lane*16
typedef const __attribute__((address_space(1))) void g_void;
typedef __attribute__((address_space(3))) void l_void;
__device__ __forceinline__ void gload16(const void* g, void* l) {
    __builtin_amdgcn_global_load_lds((g_void*)g, (l_void*)l, 16, 0, 0);
}

// ---------------- Stage 0: weight convert fp32 -> bf16, pre-tiled+swizzled ----------------
// wcat2: 12 tiles of [n(128)][kk(64)]; element (kb,n,kk) at kb*8192 + n*64 + (kk ^ ((n&7)<<3))
// wup2:  [n(768)][kk(64)] with kk ^ ((n&7)<<3)  (up_w rows)
__global__ void k_cvt(const float* __restrict__ w1, const float* __restrict__ dw,
                      const float* __restrict__ uw,
                      ushort* __restrict__ wcat2, ushort* __restrict__ wup2)
{
    const int f = (blockIdx.x * 256 + threadIdx.x) * 4;   // 147456 total
    float4 v;
    size_t dst;
    ushort* base;
    if (f < 98304) {
        int n, k;
        if (f < 49152) { n = f / 768;            k = f % 768; v = *(const float4*)(w1 + (size_t)n * 768 + k); }
        else           { int g = f - 49152; n = 64 + g / 768; k = g % 768; v = *(const float4*)(dw + (size_t)(n - 64) * 768 + k); }
        const int kb = k >> 6, kk = k & 63;
        dst  = (size_t)kb * 8192 + n * 64 + (kk ^ ((n & 7) << 3));
        base = wcat2;
    } else {
        const int g = f - 98304;                 // over [768][64]
        const int n = g >> 6, kk = g & 63;
        v = *(const float4*)(uw + g);
        dst  = (size_t)n * 64 + (kk ^ ((n & 7) << 3));
        base = wup2;
    }
    union { ushort u[4]; uint2 p; } o;
    o.u[0] = f2bf(v.x); o.u[1] = f2bf(v.y); o.u[2] = f2bf(v.z); o.u[3] = f2bf(v.w);
    *(uint2*)(base + dst) = o.p;
}

// ---------------- Stage 1+4: MFMA GEMM  M=25088 N=128 K=768 ----------------
// block 32m x 128n, 4 waves = 1m x 4n grid, wave-tile 32x32. 784 blocks.
__global__ __launch_bounds__(256)
void k_gemm_md(const float* __restrict__ x, const ushort* __restrict__ wcat2,
               const float* __restrict__ b1, const float* __restrict__ db,
               float* __restrict__ hbuf, ushort* __restrict__ xact)
{
    __shared__ ushort As[32 * 64];    //  4 KB, [m][k] swizzled
    __shared__ ushort Bs[128 * 64];   // 16 KB, linear image of wcat2 tile (pre-swizzled)
    const int t = threadIdx.x;
    const int wid = t >> 6, lane = t & 63;
    const int lo = lane & 15, hi = lane >> 4;
    const int bm = blockIdx.x;                 // 784

    f32x4 acc[2][2] = {};

    const int arow = t >> 3, akq = t & 7;      // 256 thr cover 32 rows x 8 ksegs
    const float* asrc = x + (size_t)(bm * 32 + arow) * C_ + akq * 8;

    float4 p0 = *(const float4*)(asrc);
    float4 p1 = *(const float4*)(asrc + 4);

    for (int k0 = 0; k0 < C_; k0 += 64) {
        __syncthreads();
        {   // store A tile from prefetch regs (fp32 -> bf16)
            union { ushort u[8]; float4 v; } tmp;
            tmp.u[0] = f2bf(p0.x); tmp.u[1] = f2bf(p0.y);
            tmp.u[2] = f2bf(p0.z); tmp.u[3] = f2bf(p0.w);
            tmp.u[4] = f2bf(p1.x); tmp.u[5] = f2bf(p1.y);
            tmp.u[6] = f2bf(p1.z); tmp.u[7] = f2bf(p1.w);
            *(float4*)swz(As, arow, akq * 16) = tmp.v;
        }
        {   // B tile: async DMA, 16 chunks of 1 KB (4 per wave) == 16 KB == Bs
            const ushort* bsrc = wcat2 + (size_t)(k0 >> 6) * 8192;
            #pragma unroll
            for (int c = 0; c < 4; ++c) {
                const int cbase = (wid * 4 + c) * 512;
                gload16(bsrc + cbase + lane * 8, (ushort*)Bs + cbase);
            }
        }
        if (k0 + 64 < C_) {
            p0 = *(const float4*)(asrc + k0 + 64);
            p1 = *(const float4*)(asrc + k0 + 68);
        }
        __syncthreads();   // compiler-inserted vmcnt(0) drains the gload_lds

        #pragma unroll
        for (int ks = 0; ks < 2; ++ks) {
            bf16x8 a[2], b[2];
            #pragma unroll
            for (int i = 0; i < 2; ++i)
                a[i] = *(const bf16x8*)swz(As, i * 16 + lo, ks * 64 + hi * 16);
            #pragma unroll
            for (int j = 0; j < 2; ++j)
                b[j] = *(const bf16x8*)swz(Bs, wid * 32 + j * 16 + lo, ks * 64 + hi * 16);
            #pragma unroll
            for (int i = 0; i < 2; ++i)
                #pragma unroll
                for (int j = 0; j < 2; ++j)
                    acc[i][j] = __builtin_amdgcn_mfma_f32_16x16x32_bf16(a[i], b[j], acc[i][j], 0, 0, 0);
        }
    }

    #pragma unroll
    for (int j = 0; j < 2; ++j) {
        const int n = wid * 32 + j * 16 + lo;    // 0..127, uniform half per wave
        if (n < 64) {
            const float bias = b1[n];
            #pragma unroll
            for (int i = 0; i < 2; ++i)
                #pragma unroll
                for (int r = 0; r < 4; ++r) {
                    int pos = bm * 32 + i * 16 + hi * 4 + r;
                    hbuf[(size_t)pos * 64 + n] = relu(acc[i][j][r] + bias);
                }
        } else {
            const float bias = db[n - 64];
            #pragma unroll
            for (int i = 0; i < 2; ++i)
                #pragma unroll
                for (int r = 0; r < 4; ++r) {
                    int pos = bm * 32 + i * 16 + hi * 4 + r;
                    xact[(size_t)pos * 64 + (n - 64)] = f2bf(qgelu(acc[i][j][r] + bias));
                }
        }
    }
}

// ---------------- Stage 2a: partial spatial sum (b, quarter) ----------------
__global__ void k_reduce1(const float* __restrict__ hbuf, float* __restrict__ partial)
{
    __shared__ float part[16][EMB_];
    const int b = blockIdx.x, q = blockIdx.y;
    const int tid = threadIdx.x;
    const int e4 = tid & 15, pc = tid >> 4;

    const float* base = hbuf + ((size_t)b * HW_ + q * 196) * 64 + e4 * 4;
    float4 acc = make_float4(0.f, 0.f, 0.f, 0.f);
    for (int i = pc; i < 196; i += 16) {
        float4 v = *(const float4*)(base + (size_t)i * 64);
        acc.x += v.x; acc.y += v.y; acc.z += v.z; acc.w += v.w;
    }
    part[pc][e4 * 4 + 0] = acc.x;
    part[pc][e4 * 4 + 1] = acc.y;
    part[pc][e4 * 4 + 2] = acc.z;
    part[pc][e4 * 4 + 3] = acc.w;
    __syncthreads();
    if (tid < EMB_) {
        float s = 0.f;
        #pragma unroll
        for (int c = 0; c < 16; ++c) s += part[c][tid];
        partial[(size_t)(b * 4 + q) * EMB_ + tid] = s;
    }
}

// ---------------- Stage 2b+3 fused: mean + meta2 + hypernet ----------------
__global__ void k_hyper(const float* __restrict__ partial, const float* __restrict__ layer_emb,
                        const float* __restrict__ w2, const float* __restrict__ b2,
                        const float* __restrict__ hyper_w, const float* __restrict__ hyper_b,
                        ushort* __restrict__ cwb)
{
    __shared__ float w2L[64][65];      // padded: dot reads conflict-free
    __shared__ float hmL[8][EMB_];
    __shared__ float fusedL[8][EMB_];
    const int tid = threadIdx.x;
    const int b0 = blockIdx.y * 8;

    for (int i = tid; i < 1024; i += 256) {
        int r = i >> 4, c = (i & 15) * 4;
        float4 v = *(const float4*)(w2 + (size_t)r * 64 + c);
        w2L[r][c] = v.x; w2L[r][c + 1] = v.y; w2L[r][c + 2] = v.z; w2L[r][c + 3] = v.w;
    }
    for (int i = tid; i < 512; i += 256) {
        int bl = i >> 6, e = i & 63;
        const float* pp = partial + (size_t)((b0 + bl) * 4) * EMB_ + e;
        float s = pp[0] + pp[64] + pp[128] + pp[192];
        hmL[bl][e] = s * (1.f / HW_);
    }
    __syncthreads();
    for (int i = tid; i < 512; i += 256) {
        int bl = i >> 6, e = i & 63;
        float a0 = 0.f, a1 = 0.f, a2 = 0.f, a3 = 0.f;
        #pragma unroll
        for (int k = 0; k < EMB_; k += 4) {
            a0 = fmaf(hmL[bl][k + 0], w2L[e][k + 0], a0);
            a1 = fmaf(hmL[bl][k + 1], w2L[e][k + 1], a1);
            a2 = fmaf(hmL[bl][k + 2], w2L[e][k + 2], a2);
            a3 = fmaf(hmL[bl][k + 3], w2L[e][k + 3], a3);
        }
        fusedL[bl][e] = (a0 + a1) + (a2 + a3) + b2[e] + layer_emb[e];
    }
    __syncthreads();

    const int f    = blockIdx.x * 256 + tid;
    const int din  = f & 63;
    const int dout = (f >> 6) & 63;
    const int tap  = f >> 12;
    const int r    = (dout * 64 + din) * 9 + tap;

    float wrow[EMB_];
    const float4* hw4 = (const float4*)(hyper_w + (size_t)r * EMB_);
    #pragma unroll
    for (int i = 0; i < EMB_ / 4; ++i) {
        float4 v = hw4[i];
        wrow[i*4+0] = v.x; wrow[i*4+1] = v.y; wrow[i*4+2] = v.z; wrow[i*4+3] = v.w;
    }
    const float hb = hyper_b[r];

    for (int bl = 0; bl < 8; ++bl) {
        float a0 = 0.f, a1 = 0.f, a2 = 0.f, a3 = 0.f;
        #pragma unroll
        for (int i = 0; i < EMB_; i += 4) {
            a0 = fmaf(fusedL[bl][i+0], wrow[i+0], a0);
            a1 = fmaf(fusedL[bl][i+1], wrow[i+1], a1);
            a2 = fmaf(fusedL[bl][i+2], wrow[i+2], a2);
            a3 = fmaf(fusedL[bl][i+3], wrow[i+3], a3);
        }
        cwb[(size_t)(b0 + bl) * CWROWS + f] = f2bf((a0 + a1) + (a2 + a3) + hb);
    }
}

// ---------------- Stage 5+6 fused: 3x3 conv + QuickGELU + adapter-up ----------------
// block = (b,h) via XCD-grouped remap, 8 waves. Conv: 2 M-tiles (w) x 4 N-tiles
// (dout), K=9x64. Then yt tile (32x64 bf16, LDS) becomes A for up-GEMM N=768 K=64.
__global__ __launch_bounds__(512)
void k_convup(const ushort* __restrict__ xact, const ushort* __restrict__ cwb,
              const ushort* __restrict__ wup2, const float* __restrict__ ub,
              float* __restrict__ out)
{
    __shared__ ushort wsl[192 * 64];   // conv weights, 24 KB; reused as Bs (16 KB)
    __shared__ ushort xs[34 * 64];     // x row + halo, 4.25 KB; reused as yt (4 KB)
    const int t = threadIdx.x;
    const int lane = t & 63;
    const int lo = lane & 15, hi = lane >> 4;
    // XCD-aware remap (T1): hardware assigns blocks round-robin over 8 XCDs by
    // blockIdx; group so each XCD sees 4 contiguous batches -> cwb+xact slices
    // stay L2-resident per XCD. Bijective on [0,896).
    const int bid = blockIdx.x;
    const int xcd = bid & 7;
    const int idx = bid >> 3;          // 0..111 = 4 batches x 28 rows
    const int b = xcd * 4 + idx / H_;
    const int h = idx % H_;
    const int mw = (t >> 6) >> 2;      // 0..1
    const int nw = (t >> 6) & 3;       // 0..3
    const int w0 = mw * 16;

    f32x4 acc = {};

    for (int kh = 0; kh < 3; ++kh) {
        const int hh = h + kh - 1;
        __syncthreads();
        const ushort* wsrc = cwb + (size_t)b * CWROWS + (size_t)kh * 3 * 4096;
        #pragma unroll
        for (int s = 0; s < 3; ++s) {
            int j = s * 512 + t;
            *(float4*)swz(wsl, j >> 3, (j & 7) * 16) = *(const float4*)(wsrc + j * 8);
        }
        if (t < 272) {
            int c = t >> 3, kseg = t & 7;
            int w = c - 1;
            float4 v = make_float4(0.f, 0.f, 0.f, 0.f);
            if (hh >= 0 && hh < H_ && w >= 0 && w < W_)
                v = *(const float4*)(xact + ((size_t)((b * H_ + hh) * W_) + w) * 64 + kseg * 8);
            *(float4*)swz(xs, c, kseg * 16) = v;
        }
        __syncthreads();
        #pragma unroll
        for (int kw = 0; kw < 3; ++kw) {
            #pragma unroll
            for (int ks = 0; ks < 2; ++ks) {
                bf16x8 a  = *(const bf16x8*)swz(xs, w0 + lo + kw, ks * 64 + hi * 16);
                bf16x8 bf = *(const bf16x8*)swz(wsl, kw * 64 + nw * 16 + lo, ks * 64 + hi * 16);
                acc = __builtin_amdgcn_mfma_f32_16x16x32_bf16(a, bf, acc, 0, 0, 0);
            }
        }
    }

    // ---- transition: qgelu tile -> yt (A-operand for up GEMM) ----
    __syncthreads();                    // all conv LDS reads complete
    ushort* yt = xs;                    // 32 rows x 64 k, swizzled (rows 28-31 = 0)
    const int dout = nw * 16 + lo;
    #pragma unroll
    for (int r = 0; r < 4; ++r) {
        int w = w0 + hi * 4 + r;
        *(ushort*)swz(yt, w, dout * 2) = f2bf(qgelu(acc[r]));
    }
    __syncthreads();                    // yt visible

    // hoist A fragments (constant across n-chunks)
    bf16x8 af[2];
    #pragma unroll
    for (int ks = 0; ks < 2; ++ks)
        af[ks] = *(const bf16x8*)swz(yt, mw * 16 + lo, ks * 64 + hi * 16);

    ushort* Bs = wsl;                   // 128 x 64 bf16 per chunk
    const size_t pos0 = (size_t)(b * H_ + h) * W_;

    for (int nc = 0; nc < 6; ++nc) {
        {   // stage Bs: 16 chunks of 1 KB (2 per wave), pre-swizzled source
            const ushort* bsrc = wup2 + (size_t)nc * 8192;
            const int wid = t >> 6;
            #pragma unroll
            for (int c = 0; c < 2; ++c) {
                const int cbase = (wid * 2 + c) * 512;
                gload16(bsrc + cbase + lane * 8, Bs + cbase);
            }
        }
        __syncthreads();                // vmcnt(0) drain

        f32x4 uacc[2] = {};
        #pragma unroll
        for (int ks = 0; ks < 2; ++ks) {
            bf16x8 bb[2];
            #pragma unroll
            for (int j = 0; j < 2; ++j)
                bb[j] = *(const bf16x8*)swz(Bs, nw * 32 + j * 16 + lo, ks * 64 + hi * 16);
            #pragma unroll
            for (int j = 0; j < 2; ++j)
                uacc[j] = __builtin_amdgcn_mfma_f32_16x16x32_bf16(af[ks], bb[j], uacc[j], 0, 0, 0);
        }

        #pragma unroll
        for (int j = 0; j < 2; ++j) {
            const int n = nc * 128 + nw * 32 + j * 16 + lo;
            const float bias = ub[n];
            #pragma unroll
            for (int r = 0; r < 4; ++r) {
                int m = mw * 16 + hi * 4 + r;
                if (m < W_)
                    out[(pos0 + m) * C_ + n] = uacc[j][r] + bias;
            }
        }
        __syncthreads();                // Bs reads done before next overwrite
    }
}

extern "C" void kernel_launch(void* const* d_in, const int* in_sizes, int n_in,
                              void* d_out, int out_size, void* d_ws, size_t ws_size,
                              hipStream_t stream) {
    const float* x         = (const float*)d_in[0];
    const float* meta_w1   = (const float*)d_in[1];
    const float* meta_b1   = (const float*)d_in[2];
    const float* meta_w2   = (const float*)d_in[3];
    const float* meta_b2   = (const float*)d_in[4];
    const float* layer_emb = (const float*)d_in[5];
    const float* hyper_w   = (const float*)d_in[6];
    const float* hyper_b   = (const float*)d_in[7];
    const float* down_w    = (const float*)d_in[8];
    const float* down_b    = (const float*)d_in[9];
    const float* up_w      = (const float*)d_in[10];
    const float* up_b      = (const float*)d_in[11];
    float* out = (float*)d_out;

    char* p = (char*)d_ws;
    float*  hbuf    = (float*)p;           p += (size_t)NPOS * 64 * 4;
    ushort* xact    = (ushort*)p;          p += (size_t)NPOS * 64 * 2;
    float*  partial = (float*)p;           p += (size_t)B_ * 4 * EMB_ * 4;
    ushort* cwb     = (ushort*)p;          p += (size_t)B_ * CWROWS * 2;
    ushort* wcat2   = (ushort*)p;          p += (size_t)128 * C_ * 2;
    ushort* wup2    = (ushort*)p;

    k_cvt<<<144, 256, 0, stream>>>(meta_w1, down_w, up_w, wcat2, wup2);
    k_gemm_md<<<NPOS / 32, 256, 0, stream>>>(x, wcat2, meta_b1, down_b, hbuf, xact);
    k_reduce1<<<dim3(B_, 4), 256, 0, stream>>>(hbuf, partial);
    dim3 hgrid(CWROWS / 256, B_ / 8);
    k_hyper<<<hgrid, 256, 0, stream>>>(partial, layer_emb, meta_w2, meta_b2,
                                       hyper_w, hyper_b, cwb);
    k_convup<<<B_ * H_, 512, 0, stream>>>(xact, cwb, wup2, up_b, out);
}